// Round 1
// baseline (405.798 us; speedup 1.0000x reference)
//
#include <hip/hip_runtime.h>

#define DMODEL 256
#define DCH 128
#define NLAYER 3
#define LN_EPS 1e-5f

// ---------------- CSR build ----------------

__global__ __launch_bounds__(256) void hist_kernel(const int* __restrict__ row,
    const int* __restrict__ col, int* cnt_row, int* cnt_col, int E) {
  int e = blockIdx.x * 256 + threadIdx.x;
  if (e < E) {
    atomicAdd(&cnt_row[row[e]], 1);
    atomicAdd(&cnt_col[col[e]], 1);
  }
}

__global__ __launch_bounds__(256) void dis_kernel(const int* __restrict__ cnt_row,
    float* __restrict__ dis, int N) {
  int i = blockIdx.x * 256 + threadIdx.x;
  if (i < N) dis[i] = rsqrtf((float)(cnt_row[i] + 1));  // +1 = self-loop
}

// exclusive scan of cnt_col -> indptr (and a second copy into cursor)
__global__ __launch_bounds__(256) void scan_kernel(const int* __restrict__ cnt,
    int* __restrict__ indptr, int* __restrict__ cursor, int N, int E) {
  __shared__ int buf[256];
  __shared__ int carry_s;
  int t = threadIdx.x;
  if (t == 0) carry_s = 0;
  __syncthreads();
  for (int base = 0; base < N; base += 256) {
    int v = (base + t < N) ? cnt[base + t] : 0;
    buf[t] = v;
    __syncthreads();
    for (int off = 1; off < 256; off <<= 1) {  // Hillis-Steele inclusive
      int add = (t >= off) ? buf[t - off] : 0;
      __syncthreads();
      buf[t] += add;
      __syncthreads();
    }
    int excl = carry_s + buf[t] - v;
    if (base + t < N) { indptr[base + t] = excl; cursor[base + t] = excl; }
    __syncthreads();
    if (t == 0) carry_s += buf[255];
    __syncthreads();
  }
  if (t == 0) indptr[N] = E;
}

__global__ __launch_bounds__(256) void fill_kernel(const int* __restrict__ row,
    const int* __restrict__ col, int* cursor, int* __restrict__ idx, int E) {
  int e = blockIdx.x * 256 + threadIdx.x;
  if (e < E) {
    int pos = atomicAdd(&cursor[col[e]], 1);
    idx[pos] = row[e];
  }
}

// ---------------- per-layer linear: ht = [x_c @ Wc^T + bc, x_p @ Wp^T + bp] ----------------
// grid: (N/16, 2). blockIdx.y selects content/position half.
// 256 threads: o = t&127 (output dim), g = t>>7; each thread computes 8 node-rows.

__global__ __launch_bounds__(256) void gemm_kernel(const float* __restrict__ x,
    const float* __restrict__ Wc, const float* __restrict__ bc,
    const float* __restrict__ Wp, const float* __restrict__ bp,
    float* __restrict__ ht, int layer, int Nn) {
  int h = blockIdx.y;
  const float* __restrict__ W = (h ? Wp : Wc) + (size_t)layer * DCH * DCH;
  const float* __restrict__ b = (h ? bp : bc) + (size_t)layer * DCH;
  int i0 = blockIdx.x * 16;
  int t = threadIdx.x;
  int o = t & 127;
  int g = t >> 7;

  __shared__ float xs[16][128];
  __shared__ float Ws[32][129];  // +1 pad: avoid 32-way bank conflict on write

  for (int idx = t; idx < 16 * 128; idx += 256) {
    int r = idx >> 7, c = idx & 127;
    int gi = i0 + r;
    xs[r][c] = (gi < Nn) ? x[(size_t)gi * DMODEL + h * DCH + c] : 0.f;
  }

  float acc[8];
#pragma unroll
  for (int r = 0; r < 8; r++) acc[r] = 0.f;

  for (int kc = 0; kc < 128; kc += 32) {
    __syncthreads();
    for (int idx = t; idx < 32 * 128; idx += 256) {
      int oo = idx >> 5, kk = idx & 31;
      Ws[kk][oo] = W[oo * 128 + kc + kk];
    }
    __syncthreads();
#pragma unroll
    for (int k = 0; k < 32; k++) {
      float w = Ws[k][o];
#pragma unroll
      for (int r = 0; r < 8; r++) acc[r] += xs[g + 2 * r][kc + k] * w;
    }
  }

  float bias = b[o];
#pragma unroll
  for (int r = 0; r < 8; r++) {
    int gi = i0 + g + 2 * r;
    if (gi < Nn) ht[(size_t)gi * DMODEL + h * DCH + o] = acc[r] + bias;
  }
}

// ---------------- aggregation + LayerNorm + ReLU + residual ----------------
// one block per destination node; thread t owns dim t of 256.

__global__ __launch_bounds__(256) void agg_kernel(const float* __restrict__ xin,
    const float* __restrict__ ht, float* __restrict__ xout,
    const float* __restrict__ dis, const int* __restrict__ indptr,
    const int* __restrict__ idx, const float* __restrict__ gamma,
    const float* __restrict__ beta, int relu) {
  int i = blockIdx.x;
  int t = threadIdx.x;
  float di = dis[i];
  float acc = di * di * ht[(size_t)i * DMODEL + t];  // self-loop
  int s = indptr[i], e = indptr[i + 1];

  __shared__ int s_src[256];
  __shared__ float s_w[256];
  for (int base = s; base < e; base += 256) {
    int n = min(256, e - base);
    __syncthreads();
    if (t < n) {
      int sr = idx[base + t];
      s_src[t] = sr;
      s_w[t] = dis[sr] * di;
    }
    __syncthreads();
    for (int j = 0; j < n; ++j)
      acc += s_w[j] * ht[(size_t)s_src[j] * DMODEL + t];
  }

  // block LayerNorm over 256 dims
  float v1 = acc, v2 = acc * acc;
#pragma unroll
  for (int o = 32; o > 0; o >>= 1) {
    v1 += __shfl_down(v1, o);
    v2 += __shfl_down(v2, o);
  }
  __shared__ float w1[4], w2[4];
  int wid = t >> 6, lane = t & 63;
  __syncthreads();
  if (lane == 0) { w1[wid] = v1; w2[wid] = v2; }
  __syncthreads();
  float s1 = w1[0] + w1[1] + w1[2] + w1[3];
  float s2 = w2[0] + w2[1] + w2[2] + w2[3];
  float mu = s1 * (1.0f / DMODEL);
  float var = s2 * (1.0f / DMODEL) - mu * mu;
  float y = (acc - mu) * rsqrtf(var + LN_EPS) * gamma[t] + beta[t];
  if (relu) y = fmaxf(y, 0.f);
  xout[(size_t)i * DMODEL + t] = xin[(size_t)i * DMODEL + t] + y;
}

__global__ __launch_bounds__(256) void gather_kernel(const float* __restrict__ xf,
    const int* __restrict__ noi, float* __restrict__ out) {
  int k = blockIdx.x;
  int t = threadIdx.x;
  out[(size_t)k * DMODEL + t] = xf[(size_t)noi[k] * DMODEL + t];
}

extern "C" void kernel_launch(void* const* d_in, const int* in_sizes, int n_in,
                              void* d_out, int out_size, void* d_ws, size_t ws_size,
                              hipStream_t stream) {
  const float* x     = (const float*)d_in[0];
  const int*   edges = (const int*)d_in[1];
  const int*   noi   = (const int*)d_in[2];
  const float* Wc    = (const float*)d_in[3];
  const float* bc    = (const float*)d_in[4];
  const float* Wp    = (const float*)d_in[5];
  const float* bp    = (const float*)d_in[6];
  const float* gamma = (const float*)d_in[7];
  const float* beta  = (const float*)d_in[8];

  int N = in_sizes[0] / DMODEL;
  int E = in_sizes[1] / 2;
  int K = in_sizes[2];
  const int* row = edges;      // source
  const int* col = edges + E;  // destination

  char* base = (char*)d_ws;
  size_t off = 0;
  auto alloc = [&](size_t bytes) -> void* {
    void* p = base + off;
    off += (bytes + 255) & ~(size_t)255;
    return p;
  };

  float* xA      = (float*)alloc((size_t)N * DMODEL * 4);
  float* xB      = (float*)alloc((size_t)N * DMODEL * 4);
  float* ht      = (float*)alloc((size_t)N * DMODEL * 4);
  float* dis     = (float*)alloc((size_t)N * 4);
  int*   cnt_row = (int*)alloc((size_t)N * 4);
  int*   cnt_col = (int*)alloc((size_t)N * 4);
  int*   indptr  = (int*)alloc((size_t)(N + 1) * 4);
  int*   cursor  = (int*)alloc((size_t)N * 4);
  int*   idx     = (int*)alloc((size_t)E * 4);

  hipMemsetAsync(cnt_row, 0, (size_t)N * 4, stream);
  hipMemsetAsync(cnt_col, 0, (size_t)N * 4, stream);

  int eb = (E + 255) / 256;
  int nb = (N + 255) / 256;
  hist_kernel<<<eb, 256, 0, stream>>>(row, col, cnt_row, cnt_col, E);
  dis_kernel<<<nb, 256, 0, stream>>>(cnt_row, dis, N);
  scan_kernel<<<1, 256, 0, stream>>>(cnt_col, indptr, cursor, N, E);
  fill_kernel<<<eb, 256, 0, stream>>>(row, col, cursor, idx, E);

  const float* cur_in = x;
  float* bufs[2] = {xA, xB};
  for (int l = 0; l < NLAYER; ++l) {
    float* cur_out = bufs[l & 1];
    dim3 ggrid((N + 15) / 16, 2);
    gemm_kernel<<<ggrid, 256, 0, stream>>>(cur_in, Wc, bc, Wp, bp, ht, l, N);
    agg_kernel<<<N, 256, 0, stream>>>(cur_in, ht, cur_out, dis, indptr, idx,
                                      gamma + (size_t)l * DMODEL,
                                      beta + (size_t)l * DMODEL,
                                      (l < NLAYER - 1) ? 1 : 0);
    cur_in = cur_out;
  }
  gather_kernel<<<K, 256, 0, stream>>>(cur_in, noi, (float*)d_out);
}

// Round 5
// 274.418 us; speedup vs baseline: 1.4788x; 1.4788x over previous
//
#include <hip/hip_runtime.h>

#define DMODEL 256
#define DCH 128
#define NLAYER 3
#define LN_EPS 1e-5f

__device__ __forceinline__ unsigned short f2bf(float f) {
  unsigned int u = __float_as_uint(f);
  unsigned int r = (u + 0x7FFF + ((u >> 16) & 1)) >> 16;  // RNE
  return (unsigned short)r;
}

// ---------------- CSR build ----------------

__global__ __launch_bounds__(256) void hist_kernel(const int* __restrict__ row,
    const int* __restrict__ col, int* cnt_row, int* cnt_col, int E) {
  int e = blockIdx.x * 256 + threadIdx.x;
  if (e < E) {
    atomicAdd(&cnt_row[row[e]], 1);
    atomicAdd(&cnt_col[col[e]], 1);
  }
}

// one block: dis = rsqrt(cnt_row+1); exclusive scan of cnt_col -> indptr, cursor
__global__ __launch_bounds__(256) void scan_dis_kernel(
    const int* __restrict__ cnt_col, const int* __restrict__ cnt_row,
    int* __restrict__ indptr, int* __restrict__ cursor,
    float* __restrict__ dis, int N, int E) {
  int t = threadIdx.x;
  for (int i = t; i < N; i += 256) dis[i] = rsqrtf((float)(cnt_row[i] + 1));

  const int PER = (N + 255) / 256;
  int start = t * PER;
  int sum = 0;
  for (int k = 0; k < PER; ++k) {
    int i = start + k;
    if (i < N) sum += cnt_col[i];
  }
  // block exclusive scan over 256 thread-sums
  int lane = t & 63, wid = t >> 6;
  int inc = sum;
#pragma unroll
  for (int off = 1; off < 64; off <<= 1) {
    int v = __shfl_up(inc, off);
    if (lane >= off) inc += v;
  }
  __shared__ int wsum[4];
  if (lane == 63) wsum[wid] = inc;
  __syncthreads();
  int woff = 0;
  for (int w = 0; w < wid; ++w) woff += wsum[w];
  int run = woff + inc - sum;  // exclusive prefix for this thread's chunk
  for (int k = 0; k < PER; ++k) {
    int i = start + k;
    if (i < N) {
      indptr[i] = run;
      cursor[i] = run;
      run += cnt_col[i];
    }
  }
  if (t == 255) indptr[N] = E;
}

__global__ __launch_bounds__(256) void fill_kernel(const int* __restrict__ row,
    const int* __restrict__ col, int* cursor, int* __restrict__ idx, int E) {
  int e = blockIdx.x * 256 + threadIdx.x;
  if (e < E) {
    int pos = atomicAdd(&cursor[col[e]], 1);
    idx[pos] = row[e];
  }
}

// ---------------- per-layer linear -> bf16 ht ----------------
// grid: ((N+31)/32, 2); 256 threads; tile 32 rows x 128 cols, 4x4 per thread.

__global__ __launch_bounds__(256) void gemm_kernel(const float* __restrict__ x,
    const float* __restrict__ Wc, const float* __restrict__ bc,
    const float* __restrict__ Wp, const float* __restrict__ bp,
    unsigned short* __restrict__ ht, int layer, int Nn) {
  int h = blockIdx.y;
  const float* __restrict__ W = (h ? Wp : Wc) + (size_t)layer * DCH * DCH;
  const float* __restrict__ b = (h ? bp : bc) + (size_t)layer * DCH;
  int i0 = blockIdx.x * 32;
  int t = threadIdx.x;
  int tx = t & 31;   // cols tx*4..+3
  int ty = t >> 5;   // rows ty*4..+3

  __shared__ float xs[32][128];
  __shared__ float Ws[32][132];  // pad 4 floats: keeps 16B alignment for float4 reads

  // stage x tile (32 rows x 128 cols), zero-pad tail rows
#pragma unroll
  for (int i = 0; i < 4; ++i) {
    int f = t + i * 256;
    int r = f >> 5, cq = f & 31;
    int gi = i0 + r;
    float4 v = make_float4(0.f, 0.f, 0.f, 0.f);
    if (gi < Nn) v = *(const float4*)&x[(size_t)gi * DMODEL + h * DCH + cq * 4];
    *(float4*)&xs[r][cq * 4] = v;
  }

  float acc[4][4];
#pragma unroll
  for (int r = 0; r < 4; ++r)
#pragma unroll
    for (int c = 0; c < 4; ++c) acc[r][c] = 0.f;

  for (int kc = 0; kc < 128; kc += 32) {
    __syncthreads();
    // stage Ws[kk][o] = W[o*128 + kc + kk]
#pragma unroll
    for (int i = 0; i < 4; ++i) {
      int f = t + i * 256;  // float4 index in [0,1024)
      int o = f >> 3;
      int kq = f & 7;
      float4 v = *(const float4*)&W[o * 128 + kc + kq * 4];
      Ws[kq * 4 + 0][o] = v.x;
      Ws[kq * 4 + 1][o] = v.y;
      Ws[kq * 4 + 2][o] = v.z;
      Ws[kq * 4 + 3][o] = v.w;
    }
    __syncthreads();
#pragma unroll 8
    for (int k = 0; k < 32; ++k) {
      float4 wv = *(const float4*)&Ws[k][tx * 4];
      float xr[4];
#pragma unroll
      for (int r = 0; r < 4; ++r) xr[r] = xs[ty * 4 + r][kc + k];
#pragma unroll
      for (int r = 0; r < 4; ++r) {
        acc[r][0] += xr[r] * wv.x;
        acc[r][1] += xr[r] * wv.y;
        acc[r][2] += xr[r] * wv.z;
        acc[r][3] += xr[r] * wv.w;
      }
    }
  }

  float4 bias = *(const float4*)&b[tx * 4];
#pragma unroll
  for (int r = 0; r < 4; ++r) {
    int gi = i0 + ty * 4 + r;
    if (gi < Nn) {
      ushort4 pk;
      pk.x = f2bf(acc[r][0] + bias.x);
      pk.y = f2bf(acc[r][1] + bias.y);
      pk.z = f2bf(acc[r][2] + bias.z);
      pk.w = f2bf(acc[r][3] + bias.w);
      *(ushort4*)&ht[(size_t)gi * DMODEL + h * DCH + tx * 4] = pk;
    }
  }
}

// ---------------- aggregation + LayerNorm (+ReLU) + residual ----------------
// 128 threads per node; thread t owns dims 2t, 2t+1.
// use_noi: block b handles node noi[b], writes row b of xout (= d_out).

__global__ __launch_bounds__(128) void agg_kernel(const float* __restrict__ xin,
    const unsigned short* __restrict__ ht, float* __restrict__ xout,
    const float* __restrict__ dis, const int* __restrict__ indptr,
    const int* __restrict__ idx, const float* __restrict__ gamma,
    const float* __restrict__ beta, const int* __restrict__ noi,
    int use_noi, int relu) {
  int b = blockIdx.x;
  int i = use_noi ? noi[b] : b;
  int t = threadIdx.x;
  float di = dis[i];
  size_t rbase = (size_t)i * DMODEL + 2 * t;

  unsigned int us = *(const unsigned int*)&ht[rbase];
  float w2s = di * di;
  float acc0 = w2s * __uint_as_float(us << 16);
  float acc1 = w2s * __uint_as_float(us & 0xFFFF0000u);

  int s = indptr[i], e = indptr[i + 1];
  __shared__ int s_src[128];
  __shared__ float s_w[128];
  for (int base = s; base < e; base += 128) {
    int n = min(128, e - base);
    __syncthreads();
    if (t < n) {
      int sr = idx[base + t];
      s_src[t] = sr;
      s_w[t] = dis[sr] * di;
    }
    __syncthreads();
    for (int j = 0; j < n; ++j) {
      unsigned int u = *(const unsigned int*)&ht[(size_t)s_src[j] * DMODEL + 2 * t];
      float w = s_w[j];
      acc0 += w * __uint_as_float(u << 16);
      acc1 += w * __uint_as_float(u & 0xFFFF0000u);
    }
  }

  // LayerNorm over 256 dims (2 per thread, 128 threads)
  float v1 = acc0 + acc1, v2 = acc0 * acc0 + acc1 * acc1;
#pragma unroll
  for (int o = 32; o > 0; o >>= 1) {
    v1 += __shfl_down(v1, o);
    v2 += __shfl_down(v2, o);
  }
  __shared__ float w1[2], w2[2];
  int wid = t >> 6, lane = t & 63;
  if (lane == 0) { w1[wid] = v1; w2[wid] = v2; }
  __syncthreads();
  float s1 = w1[0] + w1[1];
  float s2 = w2[0] + w2[1];
  float mu = s1 * (1.0f / DMODEL);
  float var = s2 * (1.0f / DMODEL) - mu * mu;
  float rs = rsqrtf(var + LN_EPS);
  float2 g = *(const float2*)&gamma[2 * t];
  float2 bb = *(const float2*)&beta[2 * t];
  float y0 = (acc0 - mu) * rs * g.x + bb.x;
  float y1 = (acc1 - mu) * rs * g.y + bb.y;
  if (relu) { y0 = fmaxf(y0, 0.f); y1 = fmaxf(y1, 0.f); }
  float2 xi = *(const float2*)&xin[rbase];
  size_t ob = (size_t)(use_noi ? b : i) * DMODEL + 2 * t;
  *(float2*)&xout[ob] = make_float2(xi.x + y0, xi.y + y1);
}

extern "C" void kernel_launch(void* const* d_in, const int* in_sizes, int n_in,
                              void* d_out, int out_size, void* d_ws, size_t ws_size,
                              hipStream_t stream) {
  const float* x     = (const float*)d_in[0];
  const int*   edges = (const int*)d_in[1];
  const int*   noi   = (const int*)d_in[2];
  const float* Wc    = (const float*)d_in[3];
  const float* bc    = (const float*)d_in[4];
  const float* Wp    = (const float*)d_in[5];
  const float* bp    = (const float*)d_in[6];
  const float* gamma = (const float*)d_in[7];
  const float* beta  = (const float*)d_in[8];

  int N = in_sizes[0] / DMODEL;
  int E = in_sizes[1] / 2;
  int K = in_sizes[2];
  const int* row = edges;      // source
  const int* col = edges + E;  // destination

  char* base = (char*)d_ws;
  size_t off = 0;
  auto alloc = [&](size_t bytes) -> void* {
    void* p = base + off;
    off += (bytes + 255) & ~(size_t)255;
    return p;
  };

  float*          xA     = (float*)alloc((size_t)N * DMODEL * 4);
  float*          xB     = (float*)alloc((size_t)N * DMODEL * 4);
  unsigned short* htb    = (unsigned short*)alloc((size_t)N * DMODEL * 2);
  float*          dis    = (float*)alloc((size_t)N * 4);
  int*            cnt    = (int*)alloc((size_t)2 * N * 4);  // [row | col]
  int*            indptr = (int*)alloc((size_t)(N + 1) * 4);
  int*            cursor = (int*)alloc((size_t)N * 4);
  int*            idx    = (int*)alloc((size_t)E * 4);

  hipMemsetAsync(cnt, 0, (size_t)2 * N * 4, stream);

  int eb = (E + 255) / 256;
  hist_kernel<<<eb, 256, 0, stream>>>(row, col, cnt, cnt + N, E);
  scan_dis_kernel<<<1, 256, 0, stream>>>(cnt + N, cnt, indptr, cursor, dis, N, E);
  fill_kernel<<<eb, 256, 0, stream>>>(row, col, cursor, idx, E);

  const float* cur_in = x;
  float* bufs[2] = {xA, xB};
  for (int l = 0; l < NLAYER; ++l) {
    dim3 ggrid((N + 31) / 32, 2);
    gemm_kernel<<<ggrid, 256, 0, stream>>>(cur_in, Wc, bc, Wp, bp, htb, l, N);
    if (l < NLAYER - 1) {
      agg_kernel<<<N, 128, 0, stream>>>(cur_in, htb, bufs[l & 1], dis, indptr, idx,
                                        gamma + (size_t)l * DMODEL,
                                        beta + (size_t)l * DMODEL,
                                        nullptr, 0, 1);
      cur_in = bufs[l & 1];
    } else {
      agg_kernel<<<K, 128, 0, stream>>>(cur_in, htb, (float*)d_out, dis, indptr, idx,
                                        gamma + (size_t)l * DMODEL,
                                        beta + (size_t)l * DMODEL,
                                        noi, 1, 0);
    }
  }
}